// Round 5
// baseline (685.344 us; speedup 1.0000x reference)
//
#include <hip/hip_runtime.h>

#define B 8
#define N 100000
#define NE 3200000
#define CHUNK_LOG 10
#define CHUNK 1024            // nodes per chunk (LDS acc = 8*1024*4 = 32 KB)
#define NCHUNK 98             // ceil(N / CHUNK)
#define CAP 70000             // per-bucket capacity (expect ~65.3k +- 0.3k)
#define SEG 12                // phase-2 blocks per chunk
#define EPB 4096              // phase-1 edges per block

// Static device scratch (graph-capture safe; recomputed fully every call).
__device__ int2  g_rec_nd[(size_t)NCHUNK * CAP];   // (me, other)   54.9 MB
__device__ float g_rec_c [(size_t)NCHUNK * CAP];   // conductance   27.4 MB
__device__ int   g_cursor[NCHUNK];
__device__ float g_heads_t[N * B];                 // node-major heads (3.2 MB)
__device__ float g_partial[(size_t)NCHUNK * SEG * CHUNK * B];   // 38.5 MB
__device__ float g_accum;

// ---------------------------------------------------------------------------
__global__ __launch_bounds__(128) void zero_kernel() {
    int i = threadIdx.x;
    if (i < NCHUNK) g_cursor[i] = 0;
    if (i == 0) g_accum = 0.0f;
}

// heads (B,N) -> heads_t (N,B): each node's 8 batch values contiguous (32 B).
__global__ __launch_bounds__(256) void transpose_kernel(
    const float* __restrict__ node_heads)
{
    int i = blockIdx.x * blockDim.x + threadIdx.x;   // i = n*8 + b
    if (i >= N * B) return;
    int n = i >> 3, b = i & 7;
    g_heads_t[i] = node_heads[b * N + n];
}

// ---------------------------------------------------------------------------
// Phase 1: flows output + bucket endpoint records by node chunk.
// Contribution to node `me` is c*(h[me]-h[other]) for BOTH endpoints.
// ---------------------------------------------------------------------------
__global__ __launch_bounds__(256) void phase1_kernel(
    const int* __restrict__ edge_index,     // (2, E) int32
    const float* __restrict__ edge_attr,    // (E, 2)
    float* __restrict__ flows_out)          // (B, E)
{
    __shared__ int s_s[EPB];
    __shared__ int s_d[EPB];
    __shared__ int hist[NCHUNK];
    int tid = threadIdx.x;
    int e0 = blockIdx.x * EPB;

    for (int i = tid; i < NCHUNK; i += 256) hist[i] = 0;
    __syncthreads();

    // pass A: block histogram of endpoint chunks; stage indices in LDS
#pragma unroll
    for (int i = 0; i < EPB / 256; ++i) {
        int idx = i * 256 + tid;
        int e = e0 + idx;
        int s = -1, d = -1;
        if (e < NE) {
            s = edge_index[e];
            d = edge_index[NE + e];
            atomicAdd(&hist[s >> CHUNK_LOG], 1);   // native ds_add_u32
            atomicAdd(&hist[d >> CHUNK_LOG], 1);
        }
        s_s[idx] = s;
        s_d[idx] = d;
    }
    __syncthreads();

    // reserve per-bucket space: NCHUNK global int atomics per block
    for (int i = tid; i < NCHUNK; i += 256)
        hist[i] = atomicAdd(&g_cursor[i], hist[i]);   // hist -> running cursor
    __syncthreads();

    // pass B: compute flows, emit records
#pragma unroll
    for (int i = 0; i < EPB / 256; ++i) {
        int idx = i * 256 + tid;
        int e = e0 + idx;
        if (e >= NE) continue;
        int s = s_s[idx];
        int d = s_d[idx];
        float c = ((const float2*)edge_attr)[e].x;

        const float4* hs4 = (const float4*)&g_heads_t[s << 3];
        const float4* hd4 = (const float4*)&g_heads_t[d << 3];
        float4 a0 = hs4[0], a1 = hs4[1];
        float4 b0 = hd4[0], b1 = hd4[1];
        flows_out[0 * NE + e] = c * (a0.x - b0.x);
        flows_out[1 * NE + e] = c * (a0.y - b0.y);
        flows_out[2 * NE + e] = c * (a0.z - b0.z);
        flows_out[3 * NE + e] = c * (a0.w - b0.w);
        flows_out[4 * NE + e] = c * (a1.x - b1.x);
        flows_out[5 * NE + e] = c * (a1.y - b1.y);
        flows_out[6 * NE + e] = c * (a1.z - b1.z);
        flows_out[7 * NE + e] = c * (a1.w - b1.w);

        int ks = s >> CHUNK_LOG;
        int ps = atomicAdd(&hist[ks], 1);           // ds_add_rtn_u32
        if (ps < CAP) {
            size_t w = (size_t)ks * CAP + ps;
            g_rec_nd[w] = make_int2(s, d);
            g_rec_c[w] = c;
        }
        int kd = d >> CHUNK_LOG;
        int pd = atomicAdd(&hist[kd], 1);
        if (pd < CAP) {
            size_t w = (size_t)kd * CAP + pd;
            g_rec_nd[w] = make_int2(d, s);
            g_rec_c[w] = c;
        }
    }
}

// ---------------------------------------------------------------------------
// Phase 2: per (chunk, segment) block accumulates records into a plane-major
// LDS accumulator with native ds_add_f32 (unsafeAtomicAdd), then writes
// partials coalesced. Plane-major: acc[b*CHUNK + node_local] -> one ds
// instruction spreads 64 random lanes over all 32 banks (~2/bank, free).
// ---------------------------------------------------------------------------
__global__ __launch_bounds__(256) void phase2_kernel() {
    __shared__ float acc[B * CHUNK];    // 32 KB -> 5 blocks/CU
    int chunk = blockIdx.x / SEG;
    int seg   = blockIdx.x % SEG;

    for (int i = threadIdx.x; i < B * CHUNK; i += 256) acc[i] = 0.0f;
    __syncthreads();

    int cnt = g_cursor[chunk];
    if (cnt > CAP) cnt = CAP;
    size_t rbase = (size_t)chunk * CAP;

    for (int r = seg * 256 + threadIdx.x; r < cnt; r += SEG * 256) {
        int2 nd  = g_rec_nd[rbase + r];     // coalesced dwordx2
        float c  = g_rec_c[rbase + r];      // coalesced dword
        int ml = nd.x & (CHUNK - 1);
        const float4* hm4 = (const float4*)&g_heads_t[nd.x << 3];
        const float4* ho4 = (const float4*)&g_heads_t[nd.y << 3];
        float4 a0 = hm4[0], a1 = hm4[1];
        float4 b0 = ho4[0], b1 = ho4[1];
        unsafeAtomicAdd(&acc[0 * CHUNK + ml], c * (a0.x - b0.x));
        unsafeAtomicAdd(&acc[1 * CHUNK + ml], c * (a0.y - b0.y));
        unsafeAtomicAdd(&acc[2 * CHUNK + ml], c * (a0.z - b0.z));
        unsafeAtomicAdd(&acc[3 * CHUNK + ml], c * (a0.w - b0.w));
        unsafeAtomicAdd(&acc[4 * CHUNK + ml], c * (a1.x - b1.x));
        unsafeAtomicAdd(&acc[5 * CHUNK + ml], c * (a1.y - b1.y));
        unsafeAtomicAdd(&acc[6 * CHUNK + ml], c * (a1.z - b1.z));
        unsafeAtomicAdd(&acc[7 * CHUNK + ml], c * (a1.w - b1.w));
    }
    __syncthreads();

    float* outp = &g_partial[(size_t)blockIdx.x * (B * CHUNK)];
    for (int i = threadIdx.x; i < B * CHUNK; i += 256) outp[i] = acc[i];
}

// ---------------------------------------------------------------------------
// Merge partials + fused continuity reduction. Thread i handles (b, n) in
// demands (B,N) layout; partial reads coalesced within each seg plane.
// ---------------------------------------------------------------------------
__global__ __launch_bounds__(256) void merge_cont_kernel(
    const float* __restrict__ demands)
{
    __shared__ float ssum[4];
    float local = 0.0f;
    int stride = gridDim.x * blockDim.x;
    for (int i = blockIdx.x * blockDim.x + threadIdx.x; i < B * N; i += stride) {
        int b = i / N, n = i - b * N;
        int chunk = n >> CHUNK_LOG;
        int loc = (n & (CHUNK - 1)) + b * CHUNK;
        float v = 0.0f;
        size_t base = (size_t)(chunk * SEG) * (B * CHUNK) + loc;
#pragma unroll
        for (int s = 0; s < SEG; ++s)
            v += g_partial[base + (size_t)s * (B * CHUNK)];
        v -= demands[i];
        local = fmaf(v, v, local);
    }
    for (int off = 32; off > 0; off >>= 1)
        local += __shfl_down(local, off, 64);
    int lane = threadIdx.x & 63, wave = threadIdx.x >> 6;
    if (lane == 0) ssum[wave] = local;
    __syncthreads();
    if (threadIdx.x == 0)
        unsafeAtomicAdd(&g_accum, ssum[0] + ssum[1] + ssum[2] + ssum[3]);
}

// ---------------------------------------------------------------------------
// Boundary loss + finalize scalars.
// ---------------------------------------------------------------------------
__global__ __launch_bounds__(512) void finalize_kernel(
    const float* __restrict__ node_heads,
    const int* __restrict__ res_nodes,      // (64,) int32
    const float* __restrict__ res_head,     // (1,)
    float* __restrict__ out)
{
    __shared__ float ssum[8];
    int t = threadIdx.x;          // 512 = B*64
    int b = t >> 6;
    int j = t & 63;
    float pred = node_heads[b * N + res_nodes[j]];
    float diff = pred - res_head[0];
    float local = diff * diff;
    for (int off = 32; off > 0; off >>= 1)
        local += __shfl_down(local, off, 64);
    if ((t & 63) == 0) ssum[t >> 6] = local;
    __syncthreads();
    if (t == 0) {
        float bsum = 0.0f;
        for (int w = 0; w < 8; ++w) bsum += ssum[w];
        float boundary = bsum / 512.0f;
        float continuity = g_accum / (float)(B * N);
        out[0] = continuity;
        out[1] = boundary;
        out[2] = continuity + boundary;     // LAMBDA_PHYSICS = 1.0
    }
}

extern "C" void kernel_launch(void* const* d_in, const int* in_sizes, int n_in,
                              void* d_out, int out_size, void* d_ws, size_t ws_size,
                              hipStream_t stream) {
    const float* node_heads = (const float*)d_in[0];
    const float* demands    = (const float*)d_in[1];
    const int*   edge_index = (const int*)d_in[2];    // int32 per harness
    const float* edge_attr  = (const float*)d_in[3];
    const int*   res_nodes  = (const int*)d_in[4];    // int32 per harness
    const float* res_head   = (const float*)d_in[5];

    float* out = (float*)d_out;   // [cont, bound, total, flows(B,E)]

    zero_kernel<<<1, 128, 0, stream>>>();
    transpose_kernel<<<(N * B + 255) / 256, 256, 0, stream>>>(node_heads);
    phase1_kernel<<<(NE + EPB - 1) / EPB, 256, 0, stream>>>(
        edge_index, edge_attr, out + 3);
    phase2_kernel<<<NCHUNK * SEG, 256, 0, stream>>>();
    merge_cont_kernel<<<1024, 256, 0, stream>>>(demands);
    finalize_kernel<<<1, 512, 0, stream>>>(node_heads, res_nodes, res_head, out);
}